// Round 1
// baseline (724.158 us; speedup 1.0000x reference)
//
#include <hip/hip_runtime.h>

#define DIM 64

// Kernel A: per-node gate dot products. One wave (64 lanes) per node.
// gd[n] = sum_k h[n][k] * W[k];  gs[n] = sum_k h[n][k] * W[64+k]
__global__ void fa_node_gates(const float* __restrict__ h,
                              const float* __restrict__ gate_W,
                              float* __restrict__ gd,
                              float* __restrict__ gs,
                              int N) {
    int gid  = blockIdx.x * blockDim.x + threadIdx.x;
    int node = gid >> 6;
    int lane = threadIdx.x & 63;
    if (node >= N) return;
    float x  = h[node * DIM + lane];
    float a  = x * gate_W[lane];
    float b  = x * gate_W[DIM + lane];
    #pragma unroll
    for (int off = 32; off >= 1; off >>= 1) {
        a += __shfl_xor(a, off, 64);
        b += __shfl_xor(b, off, 64);
    }
    if (lane == 0) {
        gd[node] = a;
        gs[node] = b;
    }
}

// fast tanh via hardware exp: tanh(x) = 1 - 2/(exp(2x)+1)
// saturates correctly for |x| large; plenty accurate for threshold 0.325
__device__ inline float fast_tanh(float x) {
    float e = __expf(2.0f * x);
    return 1.0f - 2.0f / (e + 1.0f);
}

// Kernel B: one wave per edge. All 64 lanes share the edge's scalars
// (same-address loads broadcast); lane k accumulates dim k.
__global__ void fa_edge_scatter(const float* __restrict__ h,
                                const float* __restrict__ d,
                                const float* __restrict__ gd,
                                const float* __restrict__ gs,
                                const int* __restrict__ esrc,
                                const int* __restrict__ edst,
                                const float* __restrict__ gate_b,
                                float* __restrict__ z,
                                int E) {
    int gid  = blockIdx.x * blockDim.x + threadIdx.x;
    int edge = gid >> 6;
    int lane = threadIdx.x & 63;
    if (edge >= E) return;
    int s = esrc[edge];
    int t = edst[edge];
    float g  = fast_tanh(gd[t] + gs[s] + gate_b[0]);
    float ev = g * d[t] * d[s];
    float m  = h[s * DIM + lane] * ev;
    atomicAdd(&z[t * DIM + lane], m);
}

extern "C" void kernel_launch(void* const* d_in, const int* in_sizes, int n_in,
                              void* d_out, int out_size, void* d_ws, size_t ws_size,
                              hipStream_t stream) {
    const float* h      = (const float*)d_in[0];
    const float* d      = (const float*)d_in[1];
    const float* gate_W = (const float*)d_in[2];
    const float* gate_b = (const float*)d_in[3];
    const int*   esrc   = (const int*)d_in[4];
    const int*   edst   = (const int*)d_in[5];
    float*       z      = (float*)d_out;

    int N = in_sizes[1];   // d has one entry per node
    int E = in_sizes[4];   // edge_src length

    float* gd = (float*)d_ws;
    float* gs = gd + N;

    // z must be zeroed every call (harness poisons once, never re-poisons)
    hipMemsetAsync(z, 0, (size_t)out_size * sizeof(float), stream);

    // 256 threads = 4 waves per block
    {
        int waves = N;
        int blocks = (waves + 3) / 4;
        fa_node_gates<<<blocks, 256, 0, stream>>>(h, gate_W, gd, gs, N);
    }
    {
        int waves = E;
        int blocks = (waves + 3) / 4;
        fa_edge_scatter<<<blocks, 256, 0, stream>>>(h, d, gd, gs, esrc, edst, gate_b, z, E);
    }
}

// Round 2
// 462.235 us; speedup vs baseline: 1.5666x; 1.5666x over previous
//
#include <hip/hip_runtime.h>

#define DIM 64
#define SCAN_BLOCK 256
#define SCAN_ITEMS 8
#define SCAN_CHUNK (SCAN_BLOCK * SCAN_ITEMS)

// ---------- Kernel A: per-node gate dot products (one wave per node) ----------
__global__ void fa_node_gates(const float* __restrict__ h,
                              const float* __restrict__ gate_W,
                              float* __restrict__ gd,
                              float* __restrict__ gs,
                              int N) {
    int gid  = blockIdx.x * blockDim.x + threadIdx.x;
    int node = gid >> 6;
    int lane = threadIdx.x & 63;
    if (node >= N) return;
    float x = h[node * DIM + lane];
    float a = x * gate_W[lane];
    float b = x * gate_W[DIM + lane];
    #pragma unroll
    for (int off = 32; off >= 1; off >>= 1) {
        a += __shfl_xor(a, off, 64);
        b += __shfl_xor(b, off, 64);
    }
    if (lane == 0) {
        gd[node] = a;
        gs[node] = b;
    }
}

__device__ inline float fast_tanh(float x) {
    float e = __expf(2.0f * x);
    return 1.0f - 2.0f / (e + 1.0f);
}

// ---------- Counting sort by dst ----------
__global__ void fa_hist(const int* __restrict__ edst, int* __restrict__ cnt, int E) {
    int i = blockIdx.x * blockDim.x + threadIdx.x;
    if (i < E) atomicAdd(&cnt[edst[i]], 1);
}

// phase 1: per-block totals
__global__ void fa_scan1(const int* __restrict__ cnt, int* __restrict__ bsum, int n) {
    __shared__ int lds[SCAN_BLOCK];
    int base = blockIdx.x * SCAN_CHUNK + threadIdx.x * SCAN_ITEMS;
    int s = 0;
    #pragma unroll
    for (int k = 0; k < SCAN_ITEMS; ++k) {
        int idx = base + k;
        s += (idx < n) ? cnt[idx] : 0;
    }
    lds[threadIdx.x] = s;
    __syncthreads();
    for (int d = SCAN_BLOCK / 2; d > 0; d >>= 1) {
        if (threadIdx.x < d) lds[threadIdx.x] += lds[threadIdx.x + d];
        __syncthreads();
    }
    if (threadIdx.x == 0) bsum[blockIdx.x] = lds[0];
}

// phase 2: exclusive scan of block sums (small, single thread)
__global__ void fa_scan2(int* __restrict__ bsum, int nb) {
    if (threadIdx.x == 0 && blockIdx.x == 0) {
        int run = 0;
        for (int i = 0; i < nb; ++i) {
            int v = bsum[i];
            bsum[i] = run;
            run += v;
        }
    }
}

// phase 3: full exclusive offsets; also initialize cursor copy
__global__ void fa_scan3(const int* __restrict__ cnt, const int* __restrict__ bsum,
                         int* __restrict__ off, int* __restrict__ cur, int n) {
    __shared__ int lds[SCAN_BLOCK];
    int base = blockIdx.x * SCAN_CHUNK + threadIdx.x * SCAN_ITEMS;
    int vals[SCAN_ITEMS];
    int s = 0;
    #pragma unroll
    for (int k = 0; k < SCAN_ITEMS; ++k) {
        int idx = base + k;
        vals[k] = (idx < n) ? cnt[idx] : 0;
        s += vals[k];
    }
    lds[threadIdx.x] = s;
    __syncthreads();
    // Hillis-Steele inclusive scan over thread sums
    for (int d = 1; d < SCAN_BLOCK; d <<= 1) {
        int v = (threadIdx.x >= (unsigned)d) ? lds[threadIdx.x - d] : 0;
        __syncthreads();
        lds[threadIdx.x] += v;
        __syncthreads();
    }
    int run = lds[threadIdx.x] - s + bsum[blockIdx.x];
    #pragma unroll
    for (int k = 0; k < SCAN_ITEMS; ++k) {
        int idx = base + k;
        if (idx < n) {
            off[idx] = run;
            cur[idx] = run;
            run += vals[k];
        }
    }
}

// scatter edges into CSR order; compute per-edge gate value e once
__global__ void fa_scatter(const float* __restrict__ gd, const float* __restrict__ gs,
                           const float* __restrict__ d,
                           const int* __restrict__ esrc, const int* __restrict__ edst,
                           const float* __restrict__ gate_b,
                           int* __restrict__ cur, int2* __restrict__ pairs, int E) {
    int i = blockIdx.x * blockDim.x + threadIdx.x;
    if (i >= E) return;
    int s = esrc[i];
    int t = edst[i];
    float g  = fast_tanh(gd[t] + gs[s] + gate_b[0]);
    float ev = g * d[t] * d[s];
    int pos = atomicAdd(&cur[t], 1);
    pairs[pos] = make_int2(s, __float_as_int(ev));
}

// ---------- Gather: one wave per node, register accumulation, no atomics ----------
__global__ void fa_gather(const float* __restrict__ h,
                          const int* __restrict__ off, const int* __restrict__ cnt,
                          const int2* __restrict__ pairs,
                          float* __restrict__ z, int N) {
    int gid  = blockIdx.x * blockDim.x + threadIdx.x;
    int node = gid >> 6;
    int lane = threadIdx.x & 63;
    if (node >= N) return;
    int start = off[node];
    int c     = cnt[node];
    float acc0 = 0.f, acc1 = 0.f;
    int j = 0;
    for (; j + 2 <= c; j += 2) {
        int2 p0 = pairs[start + j];
        int2 p1 = pairs[start + j + 1];
        acc0 += h[(size_t)p0.x * DIM + lane] * __int_as_float(p0.y);
        acc1 += h[(size_t)p1.x * DIM + lane] * __int_as_float(p1.y);
    }
    if (j < c) {
        int2 p = pairs[start + j];
        acc0 += h[(size_t)p.x * DIM + lane] * __int_as_float(p.y);
    }
    z[(size_t)node * DIM + lane] = acc0 + acc1;
}

// ---------- Fallback (atomic path) ----------
__global__ void fa_edge_scatter_atomic(const float* __restrict__ h,
                                       const float* __restrict__ d,
                                       const float* __restrict__ gd,
                                       const float* __restrict__ gs,
                                       const int* __restrict__ esrc,
                                       const int* __restrict__ edst,
                                       const float* __restrict__ gate_b,
                                       float* __restrict__ z, int E) {
    int gid  = blockIdx.x * blockDim.x + threadIdx.x;
    int edge = gid >> 6;
    int lane = threadIdx.x & 63;
    if (edge >= E) return;
    int s = esrc[edge];
    int t = edst[edge];
    float g  = fast_tanh(gd[t] + gs[s] + gate_b[0]);
    float ev = g * d[t] * d[s];
    atomicAdd(&z[t * DIM + lane], h[s * DIM + lane] * ev);
}

extern "C" void kernel_launch(void* const* d_in, const int* in_sizes, int n_in,
                              void* d_out, int out_size, void* d_ws, size_t ws_size,
                              hipStream_t stream) {
    const float* h      = (const float*)d_in[0];
    const float* d      = (const float*)d_in[1];
    const float* gate_W = (const float*)d_in[2];
    const float* gate_b = (const float*)d_in[3];
    const int*   esrc   = (const int*)d_in[4];
    const int*   edst   = (const int*)d_in[5];
    float*       z      = (float*)d_out;

    int N = in_sizes[1];   // d: one per node
    int E = in_sizes[4];   // edge count

    int NB = (N + SCAN_CHUNK - 1) / SCAN_CHUNK;

    // workspace layout
    char* w = (char*)d_ws;
    float* gd  = (float*)w;            w += (size_t)N * 4;
    float* gs  = (float*)w;            w += (size_t)N * 4;
    int*   cnt = (int*)w;              w += (size_t)N * 4;
    int*   off = (int*)w;              w += (size_t)N * 4;
    int*   cur = (int*)w;              w += (size_t)N * 4;
    int*   bsum = (int*)w;             w += (size_t)((NB + 15) & ~15) * 4;
    // align pairs to 8 B
    w = (char*)(((uintptr_t)w + 7) & ~(uintptr_t)7);
    int2* pairs = (int2*)w;            w += (size_t)E * 8;
    size_t required = (size_t)(w - (char*)d_ws);

    // gates (needed by both paths)
    fa_node_gates<<<(N + 3) / 4, 256, 0, stream>>>(h, gate_W, gd, gs, N);

    if (ws_size >= required) {
        // CSR path
        hipMemsetAsync(cnt, 0, (size_t)N * 4, stream);
        fa_hist<<<(E + 255) / 256, 256, 0, stream>>>(edst, cnt, E);
        fa_scan1<<<NB, SCAN_BLOCK, 0, stream>>>(cnt, bsum, N);
        fa_scan2<<<1, 64, 0, stream>>>(bsum, NB);
        fa_scan3<<<NB, SCAN_BLOCK, 0, stream>>>(cnt, bsum, off, cur, N);
        fa_scatter<<<(E + 255) / 256, 256, 0, stream>>>(gd, gs, d, esrc, edst, gate_b,
                                                        cur, pairs, E);
        fa_gather<<<(N + 3) / 4, 256, 0, stream>>>(h, off, cnt, pairs, z, N);
    } else {
        // fallback: atomic scatter
        hipMemsetAsync(z, 0, (size_t)out_size * sizeof(float), stream);
        fa_edge_scatter_atomic<<<(E + 3) / 4, 256, 0, stream>>>(h, d, gd, gs, esrc,
                                                                edst, gate_b, z, E);
    }
}

// Round 3
// 461.864 us; speedup vs baseline: 1.5679x; 1.0008x over previous
//
#include <hip/hip_runtime.h>
#include <hip/hip_bf16.h>

#define DIM 64
#define SCAN_BLOCK 256
#define SCAN_ITEMS 8
#define SCAN_CHUNK (SCAN_BLOCK * SCAN_ITEMS)
#define NXCD 8

__device__ inline float fast_tanh(float x) {
    float e = __expf(2.0f * x);
    return 1.0f - 2.0f / (e + 1.0f);
}

// ---------- Kernel A: per-node gate dots + optional bf16 copy of h ----------
__global__ void fa_node_gates(const float* __restrict__ h,
                              const float* __restrict__ gate_W,
                              float* __restrict__ gd,
                              float* __restrict__ gs,
                              __hip_bfloat16* __restrict__ hb,   // may be null
                              int N) {
    int gid  = blockIdx.x * blockDim.x + threadIdx.x;
    int node = gid >> 6;
    int lane = threadIdx.x & 63;
    if (node >= N) return;
    float x = h[(size_t)node * DIM + lane];
    if (hb) hb[(size_t)node * DIM + lane] = __float2bfloat16(x);
    float a = x * gate_W[lane];
    float b = x * gate_W[DIM + lane];
    #pragma unroll
    for (int off = 32; off >= 1; off >>= 1) {
        a += __shfl_xor(a, off, 64);
        b += __shfl_xor(b, off, 64);
    }
    if (lane == 0) {
        gd[node] = a;
        gs[node] = b;
    }
}

// ---------- Counting sort by dst ----------
__global__ void fa_hist(const int* __restrict__ edst, int* __restrict__ cnt, int E) {
    int i = blockIdx.x * blockDim.x + threadIdx.x;
    if (i < E) atomicAdd(&cnt[edst[i]], 1);
}

__global__ void fa_scan1(const int* __restrict__ cnt, int* __restrict__ bsum, int n) {
    __shared__ int lds[SCAN_BLOCK];
    int base = blockIdx.x * SCAN_CHUNK + threadIdx.x * SCAN_ITEMS;
    int s = 0;
    #pragma unroll
    for (int k = 0; k < SCAN_ITEMS; ++k) {
        int idx = base + k;
        s += (idx < n) ? cnt[idx] : 0;
    }
    lds[threadIdx.x] = s;
    __syncthreads();
    for (int d = SCAN_BLOCK / 2; d > 0; d >>= 1) {
        if (threadIdx.x < d) lds[threadIdx.x] += lds[threadIdx.x + d];
        __syncthreads();
    }
    if (threadIdx.x == 0) bsum[blockIdx.x] = lds[0];
}

__global__ void fa_scan2(int* __restrict__ bsum, int nb) {
    if (threadIdx.x == 0 && blockIdx.x == 0) {
        int run = 0;
        for (int i = 0; i < nb; ++i) {
            int v = bsum[i];
            bsum[i] = run;
            run += v;
        }
    }
}

__global__ void fa_scan3(const int* __restrict__ cnt, const int* __restrict__ bsum,
                         int* __restrict__ off, int* __restrict__ cur, int n) {
    __shared__ int lds[SCAN_BLOCK];
    int base = blockIdx.x * SCAN_CHUNK + threadIdx.x * SCAN_ITEMS;
    int vals[SCAN_ITEMS];
    int s = 0;
    #pragma unroll
    for (int k = 0; k < SCAN_ITEMS; ++k) {
        int idx = base + k;
        vals[k] = (idx < n) ? cnt[idx] : 0;
        s += vals[k];
    }
    lds[threadIdx.x] = s;
    __syncthreads();
    for (int d = 1; d < SCAN_BLOCK; d <<= 1) {
        int v = (threadIdx.x >= (unsigned)d) ? lds[threadIdx.x - d] : 0;
        __syncthreads();
        lds[threadIdx.x] += v;
        __syncthreads();
    }
    int run = lds[threadIdx.x] - s + bsum[blockIdx.x];
    #pragma unroll
    for (int k = 0; k < SCAN_ITEMS; ++k) {
        int idx = base + k;
        if (idx < n) {
            off[idx] = run;
            cur[idx] = run;
            run += vals[k];
        }
    }
}

// ---------- XCD-partitioned scatter: blockIdx%8 -> dst range ----------
__global__ void fa_scatter_xcd(const float* __restrict__ gd, const float* __restrict__ gs,
                               const float* __restrict__ d,
                               const int* __restrict__ esrc, const int* __restrict__ edst,
                               const float* __restrict__ gate_b,
                               int* __restrict__ cur, int2* __restrict__ pairs,
                               int E, int N) {
    int xcd = blockIdx.x & (NXCD - 1);
    int q   = blockIdx.x >> 3;
    int Q   = gridDim.x >> 3;
    int rsize = (N + NXCD - 1) / NXCD;
    int r0 = xcd * rsize;
    int r1 = min(N, r0 + rsize);
    float gb = gate_b[0];
    for (int i = q * blockDim.x + threadIdx.x; i < E; i += Q * blockDim.x) {
        int t = edst[i];
        if (t < r0 || t >= r1) continue;
        int s = esrc[i];
        float g  = fast_tanh(gd[t] + gs[s] + gb);
        float ev = g * d[t] * d[s];
        int pos = atomicAdd(&cur[t], 1);
        pairs[pos] = make_int2(s, __float_as_int(ev));
    }
}

// ---------- Gather (bf16 h), one wave per node, XCD dst-range mapping ----------
__global__ void fa_gather_bf16(const __hip_bfloat16* __restrict__ hb,
                               const int* __restrict__ off, const int* __restrict__ cnt,
                               const int2* __restrict__ pairs,
                               float* __restrict__ z, int N) {
    int xcd = blockIdx.x & (NXCD - 1);
    int q   = blockIdx.x >> 3;
    int lane = threadIdx.x & 63;
    int widx = q * (blockDim.x >> 6) + (threadIdx.x >> 6);
    int rsize = (N + NXCD - 1) / NXCD;
    int r0 = xcd * rsize;
    int node = r0 + widx;
    if (widx >= rsize || node >= N) return;
    int start = off[node];
    int c     = cnt[node];
    float acc0 = 0.f, acc1 = 0.f;
    int j = 0;
    for (; j + 2 <= c; j += 2) {
        int2 p0 = pairs[start + j];
        int2 p1 = pairs[start + j + 1];
        acc0 += __bfloat162float(hb[(size_t)p0.x * DIM + lane]) * __int_as_float(p0.y);
        acc1 += __bfloat162float(hb[(size_t)p1.x * DIM + lane]) * __int_as_float(p1.y);
    }
    if (j < c) {
        int2 p = pairs[start + j];
        acc0 += __bfloat162float(hb[(size_t)p.x * DIM + lane]) * __int_as_float(p.y);
    }
    z[(size_t)node * DIM + lane] = acc0 + acc1;
}

// ---------- Gather (f32 h) fallback, same mapping ----------
__global__ void fa_gather_f32(const float* __restrict__ h,
                              const int* __restrict__ off, const int* __restrict__ cnt,
                              const int2* __restrict__ pairs,
                              float* __restrict__ z, int N) {
    int xcd = blockIdx.x & (NXCD - 1);
    int q   = blockIdx.x >> 3;
    int lane = threadIdx.x & 63;
    int widx = q * (blockDim.x >> 6) + (threadIdx.x >> 6);
    int rsize = (N + NXCD - 1) / NXCD;
    int r0 = xcd * rsize;
    int node = r0 + widx;
    if (widx >= rsize || node >= N) return;
    int start = off[node];
    int c     = cnt[node];
    float acc0 = 0.f, acc1 = 0.f;
    int j = 0;
    for (; j + 2 <= c; j += 2) {
        int2 p0 = pairs[start + j];
        int2 p1 = pairs[start + j + 1];
        acc0 += h[(size_t)p0.x * DIM + lane] * __int_as_float(p0.y);
        acc1 += h[(size_t)p1.x * DIM + lane] * __int_as_float(p1.y);
    }
    if (j < c) {
        int2 p = pairs[start + j];
        acc0 += h[(size_t)p.x * DIM + lane] * __int_as_float(p.y);
    }
    z[(size_t)node * DIM + lane] = acc0 + acc1;
}

// ---------- Fallback (atomic path) ----------
__global__ void fa_edge_scatter_atomic(const float* __restrict__ h,
                                       const float* __restrict__ d,
                                       const float* __restrict__ gd,
                                       const float* __restrict__ gs,
                                       const int* __restrict__ esrc,
                                       const int* __restrict__ edst,
                                       const float* __restrict__ gate_b,
                                       float* __restrict__ z, int E) {
    int gid  = blockIdx.x * blockDim.x + threadIdx.x;
    int edge = gid >> 6;
    int lane = threadIdx.x & 63;
    if (edge >= E) return;
    int s = esrc[edge];
    int t = edst[edge];
    float g  = fast_tanh(gd[t] + gs[s] + gate_b[0]);
    float ev = g * d[t] * d[s];
    atomicAdd(&z[t * DIM + lane], h[s * DIM + lane] * ev);
}

extern "C" void kernel_launch(void* const* d_in, const int* in_sizes, int n_in,
                              void* d_out, int out_size, void* d_ws, size_t ws_size,
                              hipStream_t stream) {
    const float* h      = (const float*)d_in[0];
    const float* d      = (const float*)d_in[1];
    const float* gate_W = (const float*)d_in[2];
    const float* gate_b = (const float*)d_in[3];
    const int*   esrc   = (const int*)d_in[4];
    const int*   edst   = (const int*)d_in[5];
    float*       z      = (float*)d_out;

    int N = in_sizes[1];
    int E = in_sizes[4];

    int NB = (N + SCAN_CHUNK - 1) / SCAN_CHUNK;

    // workspace layout
    char* w = (char*)d_ws;
    float* gd  = (float*)w;            w += (size_t)N * 4;
    float* gs  = (float*)w;            w += (size_t)N * 4;
    int*   cnt = (int*)w;              w += (size_t)N * 4;
    int*   off = (int*)w;              w += (size_t)N * 4;
    int*   cur = (int*)w;              w += (size_t)N * 4;
    int*   bsum = (int*)w;             w += (size_t)((NB + 15) & ~15) * 4;
    w = (char*)(((uintptr_t)w + 7) & ~(uintptr_t)7);
    int2* pairs = (int2*)w;            w += (size_t)E * 8;
    size_t csr_required = (size_t)(w - (char*)d_ws);
    __hip_bfloat16* hb = (__hip_bfloat16*)w;
    size_t full_required = csr_required + (size_t)N * DIM * 2;

    bool use_csr  = ws_size >= csr_required;
    bool use_bf16 = ws_size >= full_required;

    fa_node_gates<<<(N + 3) / 4, 256, 0, stream>>>(h, gate_W, gd, gs,
                                                   use_bf16 ? hb : (__hip_bfloat16*)nullptr, N);

    if (use_csr) {
        hipMemsetAsync(cnt, 0, (size_t)N * 4, stream);
        fa_hist<<<(E + 255) / 256, 256, 0, stream>>>(edst, cnt, E);
        fa_scan1<<<NB, SCAN_BLOCK, 0, stream>>>(cnt, bsum, N);
        fa_scan2<<<1, 64, 0, stream>>>(bsum, NB);
        fa_scan3<<<NB, SCAN_BLOCK, 0, stream>>>(cnt, bsum, off, cur, N);
        // 8 XCD groups x 256 blocks
        fa_scatter_xcd<<<NXCD * 256, 256, 0, stream>>>(gd, gs, d, esrc, edst, gate_b,
                                                       cur, pairs, E, N);
        int rsize = (N + NXCD - 1) / NXCD;
        int bpx   = (rsize + 3) / 4;           // 4 waves per block
        if (use_bf16)
            fa_gather_bf16<<<NXCD * bpx, 256, 0, stream>>>(hb, off, cnt, pairs, z, N);
        else
            fa_gather_f32<<<NXCD * bpx, 256, 0, stream>>>(h, off, cnt, pairs, z, N);
    } else {
        hipMemsetAsync(z, 0, (size_t)out_size * sizeof(float), stream);
        fa_edge_scatter_atomic<<<(E + 3) / 4, 256, 0, stream>>>(h, d, gd, gs, esrc,
                                                                edst, gate_b, z, E);
    }
}